// Round 20
// baseline (1252.002 us; speedup 1.0000x reference)
//
#include <hip/hip_runtime.h>
#include <hip/hip_fp16.h>
#include <hip/hip_cooperative_groups.h>
#include <math.h>

#define LEAKY(x) ((x) > 0.f ? (x) : 0.01f * (x))
#define BK_SHIFT 9            // 512 nodes per bucket
#define NBMAX 128             // supports N <= 65536
#define BCAP 16384            // edges capacity per bucket (mean 8192 + ~90 sigma)

namespace cg = cooperative_groups;

typedef _Float16 half8 __attribute__((ext_vector_type(8)));
typedef float f32x4 __attribute__((ext_vector_type(4)));

__device__ __forceinline__ void add4(float4& acc, const float4& v) {
    acc.x += v.x; acc.y += v.y; acc.z += v.z; acc.w += v.w;
}

__device__ __forceinline__ float2 h2f(unsigned u) {
    return __half22float2(*(const __half2*)&u);
}

__device__ __forceinline__ int lower_bound(const int* b, int n, int v) {
    int lo = 0, hi = n;
    while (lo < hi) {
        int m = (lo + hi) >> 1;
        if (b[m] < v) lo = m + 1; else hi = m;
    }
    return lo;
}

// Pass 1 of CSR fill: LDS counting-sort 2048-edge chunks by 512-node bucket.
__global__ __launch_bounds__(256) void bin_kernel(const int* __restrict__ src,
                                                  const int* __restrict__ dst,
                                                  int* __restrict__ bfill,
                                                  uint2* __restrict__ tmp,
                                                  int E, int nb) {
    __shared__ int hist[NBMAX];
    __shared__ int scanbuf[NBMAX];
    __shared__ int lofs[NBMAX];
    __shared__ int adj[NBMAX];
    __shared__ uint2 buf[2048];
    __shared__ unsigned char bkt_of[2048];
    int base = blockIdx.x * 2048;
    int cnt = min(2048, E - base);
    int tid = threadIdx.x;
    for (int b = tid; b < NBMAX; b += 256) hist[b] = 0;
    __syncthreads();
    int es[8], ed[8];
#pragma unroll
    for (int k = 0; k < 8; ++k) {
        int l = tid + k * 256;
        if (l < cnt) {
            es[k] = src[base + l];
            ed[k] = dst[base + l];
            atomicAdd(&hist[ed[k] >> BK_SHIFT], 1);
        }
    }
    __syncthreads();
    if (tid < NBMAX) scanbuf[tid] = hist[tid];
    __syncthreads();
    for (int off = 1; off < NBMAX; off <<= 1) {
        int t = (tid < NBMAX && tid >= off) ? scanbuf[tid - off] : 0;
        __syncthreads();
        if (tid < NBMAX) scanbuf[tid] += t;
        __syncthreads();
    }
    if (tid < nb) {
        int cb = hist[tid];
        int start = scanbuf[tid] - cb;   // exclusive (position in buf)
        lofs[tid] = start;
        int g = (cb > 0) ? atomicAdd(&bfill[tid], cb) : 0;
        adj[tid] = tid * BCAP + g - start;  // buf idx -> tmp idx shift
    }
    __syncthreads();
#pragma unroll
    for (int k = 0; k < 8; ++k) {
        int l = tid + k * 256;
        if (l < cnt) {
            int b = ed[k] >> BK_SHIFT;
            int r = atomicAdd(&lofs[b], 1);
            buf[r] = make_uint2((unsigned)es[k], (unsigned)ed[k]);
            bkt_of[r] = (unsigned char)b;
        }
    }
    __syncthreads();
    for (int j = tid; j < cnt; j += 256) {
        int b = bkt_of[j];
        tmp[adj[b] + j] = buf[j];
    }
}

// Pass 2: per-bucket degree hist, scan -> row_ptr, dis, Z0 pre-scale, scatter.
__global__ __launch_bounds__(512) void place2(const uint2* __restrict__ tmp,
                                              const int* __restrict__ bfill,
                                              const float* __restrict__ X,
                                              float* __restrict__ dis,
                                              int* __restrict__ row_ptr,
                                              int* __restrict__ edge_src,
                                              float* __restrict__ Z0, int kq,
                                              int n, int E, int nb) {
    __shared__ int hist[512];
    __shared__ int sc[512];
    __shared__ int sbf[NBMAX];
    __shared__ int bb_s;
    int b = blockIdx.x;
    int tid = threadIdx.x;
    if (tid < NBMAX) sbf[tid] = (tid < nb) ? bfill[tid] : 0;
    hist[tid] = 0;
    __syncthreads();
    if (tid == 0) {
        int s = 0;
        for (int k = 0; k < b; ++k) s += sbf[k];
        bb_s = s;
    }
    __syncthreads();
    int bb = bb_s;
    int cnt = sbf[b];
    const uint2* mybkt = tmp + (size_t)b * BCAP;
    int node0 = b << BK_SHIFT;
    for (int j = tid; j < cnt; j += 512)
        atomicAdd(&hist[(int)mybkt[j].y - node0], 1);
    __syncthreads();
    int v = hist[tid];
    sc[tid] = v;
    __syncthreads();
    for (int off = 1; off < 512; off <<= 1) {
        int t = (tid >= off) ? sc[tid - off] : 0;
        __syncthreads();
        sc[tid] += t;
        __syncthreads();
    }
    int excl = sc[tid] - v;
    int i = node0 + tid;
    if (i < n) {
        row_ptr[i] = bb + excl;
        float di = rsqrtf((float)(v + 1));  // +1: self-loop
        dis[i] = di;
        const float4* X4 = (const float4*)X;
        float4* Z4 = (float4*)Z0;
        for (int j = 0; j < kq; ++j) {
            float4 xv = X4[(size_t)i * kq + j];
            Z4[(size_t)i * kq + j] = make_float4(di * xv.x, di * xv.y, di * xv.z, di * xv.w);
        }
    }
    if (b == 0 && tid == 0) row_ptr[n] = E;
    __syncthreads();
    hist[tid] = bb + excl;  // reuse as LDS cursor
    __syncthreads();
    for (int j = tid; j < cnt; j += 512) {
        uint2 ev = mybkt[j];
        int pos = atomicAdd(&hist[(int)ev.y - node0], 1);
        edge_src[pos] = (int)ev.x;
    }
}

struct MegaP {
    const float* dis; const int* row_ptr; const int* edge_src; const int* batch;
    const float* Z0; __half* ZA; __half* ZB; float* H; float* Agg;
    float* pmax; float* psum;
    const float* W0; const float* b0;
    const float* W1; const float* b1;
    const float* W2; const float* b2;
    const float* W3; const float* b3;
    const float* W4; const float* b4;
    const float* Wo1; const float* bo1; const float* Wo2; const float* bo2;
    float* out; int N; int G;
};

// 96x96 MFMA gemm phase (R16-proven). Wt staged once per call; Ah per tile.
template <int SCALE, int OUTH>
__device__ void gemm96(const float* A, const float* W, const float* bias,
                       const float* dis, void* Xn, int n,
                       _Float16* Ah, _Float16* Wt) {
    constexpr int LDA = 104;
    int tid = threadIdx.x;
    for (int idx = tid; idx < 96 * 24; idx += 256) {
        int k = idx / 24, c4 = idx % 24;
        float4 v = ((const float4*)W)[(size_t)k * 24 + c4];
        int nc = c4 * 4;
        Wt[(nc + 0) * LDA + k] = (_Float16)v.x;
        Wt[(nc + 1) * LDA + k] = (_Float16)v.y;
        Wt[(nc + 2) * LDA + k] = (_Float16)v.z;
        Wt[(nc + 3) * LDA + k] = (_Float16)v.w;
    }
    __syncthreads();
    int w = tid >> 6, lane = tid & 63;
    int q = lane >> 4, c = lane & 15;
    int tiles = (n + 63) >> 6;
    for (int t = blockIdx.x; t < tiles; t += gridDim.x) {
        int i0 = t << 6;
        for (int idx = tid; idx < 64 * 24; idx += 256) {
            int r = idx / 24, c4 = idx % 24;
            int gi = i0 + r;
            float4 v = (gi < n) ? ((const float4*)A)[(size_t)gi * 24 + c4]
                                : make_float4(0.f, 0.f, 0.f, 0.f);
            _Float16* pp = &Ah[r * LDA + c4 * 4];
            pp[0] = (_Float16)v.x; pp[1] = (_Float16)v.y;
            pp[2] = (_Float16)v.z; pp[3] = (_Float16)v.w;
        }
        __syncthreads();
        half8 af[3];
#pragma unroll
        for (int kc = 0; kc < 3; ++kc)
            af[kc] = *(const half8*)&Ah[(w * 16 + c) * LDA + kc * 32 + q * 8];
        float dvals[4];
#pragma unroll
        for (int r = 0; r < 4; ++r) {
            int gi = i0 + w * 16 + q * 4 + r;
            dvals[r] = (SCALE && gi < n) ? dis[gi] : 1.f;
        }
#pragma unroll
        for (int nt = 0; nt < 6; ++nt) {
            f32x4 acc = {0.f, 0.f, 0.f, 0.f};
#pragma unroll
            for (int kc = 0; kc < 3; ++kc) {
                half8 bf = *(const half8*)&Wt[(nt * 16 + c) * LDA + kc * 32 + q * 8];
                acc = __builtin_amdgcn_mfma_f32_16x16x32_f16(af[kc], bf, acc, 0, 0, 0);
            }
            int col = nt * 16 + c;
            float bv = bias[col];
#pragma unroll
            for (int r = 0; r < 4; ++r) {
                int gi = i0 + w * 16 + q * 4 + r;
                if (gi < n) {
                    float v = acc[r] + bv;
                    v = LEAKY(v);
                    if (SCALE) v *= dvals[r];
                    if (OUTH)
                        ((_Float16*)Xn)[(size_t)gi * 96 + col] = (_Float16)v;
                    else
                        ((float*)Xn)[(size_t)gi * 96 + col] = v;
                }
            }
        }
        __syncthreads();
    }
}

// fp16 wave-per-node agg phase (R16-proven shape), wave-stride over nodes.
__device__ void agg96(const __half* Zh, const float* dis, const int* row_ptr,
                      const int* edge_src, float* A, int n) {
    int wid = blockIdx.x * 4 + (threadIdx.x >> 6);
    int lane = threadIdx.x & 63;
    int g = lane >> 3, c = lane & 7;
    int stride = gridDim.x * 4;
    for (int i = wid; i < n; i += stride) {
        float di = dis[i];
        float acc[12];
        if (g == 0) {
            const uint2* zp = (const uint2*)(Zh + (size_t)i * 96 + c * 12);
            uint2 u0 = zp[0], u1 = zp[1], u2 = zp[2];
            float2 f;
            f = h2f(u0.x); acc[0] = f.x;  acc[1] = f.y;
            f = h2f(u0.y); acc[2] = f.x;  acc[3] = f.y;
            f = h2f(u1.x); acc[4] = f.x;  acc[5] = f.y;
            f = h2f(u1.y); acc[6] = f.x;  acc[7] = f.y;
            f = h2f(u2.x); acc[8] = f.x;  acc[9] = f.y;
            f = h2f(u2.y); acc[10] = f.x; acc[11] = f.y;
        } else {
#pragma unroll
            for (int k = 0; k < 12; ++k) acc[k] = 0.f;
        }
        int re0 = row_ptr[i], re1 = row_ptr[i + 1];
#pragma unroll 4
        for (int e = re0 + g; e < re1; e += 8) {
            int s = edge_src[e];
            const uint2* zp = (const uint2*)(Zh + (size_t)s * 96 + c * 12);
            uint2 u0 = zp[0], u1 = zp[1], u2 = zp[2];
            float2 f;
            f = h2f(u0.x); acc[0] += f.x;  acc[1] += f.y;
            f = h2f(u0.y); acc[2] += f.x;  acc[3] += f.y;
            f = h2f(u1.x); acc[4] += f.x;  acc[5] += f.y;
            f = h2f(u1.y); acc[6] += f.x;  acc[7] += f.y;
            f = h2f(u2.x); acc[8] += f.x;  acc[9] += f.y;
            f = h2f(u2.y); acc[10] += f.x; acc[11] += f.y;
        }
#pragma unroll
        for (int m = 8; m < 64; m <<= 1) {
#pragma unroll
            for (int k = 0; k < 12; ++k) acc[k] += __shfl_xor(acc[k], m);
        }
        if (g == 0) {
            float4* ap = (float4*)(A + (size_t)i * 96 + c * 12);
#pragma unroll
            for (int k = 0; k < 3; ++k)
                ap[k] = make_float4(di * acc[k * 4 + 0], di * acc[k * 4 + 1],
                                    di * acc[k * 4 + 2], di * acc[k * 4 + 3]);
        }
    }
}

// Cooperative mega-kernel: agg0 | gemm_l0 | 4x(agg96|gemm96) | pool. Phases
// separated by grid.sync() — replaces 12 dispatches (~10 us launch gap each).
__global__ __launch_bounds__(256, 4) void gnn_mega(MegaP p) {
    cg::grid_group grid = cg::this_grid();
    __shared__ __align__(16) _Float16 smem[16640];  // 33280 B -> 4 blocks/CU
    _Float16* Ah = smem;
    _Float16* Wt = smem + 64 * 104;

    // ---- Phase: fp32 agg, 16-wide (wave-stride over nodes) ----
    {
        int wid = blockIdx.x * 4 + (threadIdx.x >> 6);
        int lane = threadIdx.x & 63;
        int g = lane >> 2, c = lane & 3;
        const float4* Z4 = (const float4*)p.Z0;
        int stride = gridDim.x * 4;
        for (int i = wid; i < p.N; i += stride) {
            float di = p.dis[i];
            size_t base = (size_t)i * 4 + c;
            float4 acc = (g == 0) ? Z4[base] : make_float4(0.f, 0.f, 0.f, 0.f);
            int re0 = p.row_ptr[i], re1 = p.row_ptr[i + 1];
#pragma unroll 2
            for (int e = re0 + g; e < re1; e += 16) {
                int s = p.edge_src[e];
                add4(acc, Z4[(size_t)s * 4 + c]);
            }
#pragma unroll
            for (int m = 4; m < 64; m <<= 1) {
                acc.x += __shfl_xor(acc.x, m);
                acc.y += __shfl_xor(acc.y, m);
                acc.z += __shfl_xor(acc.z, m);
                acc.w += __shfl_xor(acc.w, m);
            }
            if (g == 0)
                ((float4*)p.Agg)[base] = make_float4(di * acc.x, di * acc.y,
                                                     di * acc.z, di * acc.w);
        }
    }
    grid.sync();

    // ---- Phase: gemm_l0 (K=16 VALU) -> fp16 ZA ----
    {
        float4* Al = (float4*)smem;
        int tid = threadIdx.x;
        int tiles = (p.N + 63) >> 6;
        const float4* W4 = (const float4*)p.W0;
        for (int t = blockIdx.x; t < tiles; t += gridDim.x) {
            int i0 = t << 6;
            {
                int gi = i0 + (tid >> 2);
                Al[tid] = (gi < p.N) ? ((const float4*)p.Agg)[(size_t)i0 * 4 + tid]
                                     : make_float4(0.f, 0.f, 0.f, 0.f);
            }
            __syncthreads();
            if (tid < 192) {
                int fq = tid % 24;
                int g2 = tid / 24;
                float4 bb = ((const float4*)p.b0)[fq];
                float4 acc[8];
#pragma unroll
                for (int r = 0; r < 8; ++r) acc[r] = bb;
                for (int kc = 0; kc < 16; kc += 8) {
                    float4 w[8];
#pragma unroll
                    for (int kk = 0; kk < 8; ++kk) w[kk] = W4[(size_t)(kc + kk) * 24 + fq];
#pragma unroll
                    for (int r = 0; r < 8; ++r) {
                        const float4* ar = &Al[(g2 * 8 + r) * 4 + (kc >> 2)];
#pragma unroll
                        for (int k4 = 0; k4 < 2; ++k4) {
                            float4 a = ar[k4];
                            float4 w0 = w[4 * k4 + 0], w1 = w[4 * k4 + 1];
                            float4 w2 = w[4 * k4 + 2], w3 = w[4 * k4 + 3];
                            acc[r].x += a.x * w0.x + a.y * w1.x + a.z * w2.x + a.w * w3.x;
                            acc[r].y += a.x * w0.y + a.y * w1.y + a.z * w2.y + a.w * w3.y;
                            acc[r].z += a.x * w0.z + a.y * w1.z + a.z * w2.z + a.w * w3.z;
                            acc[r].w += a.x * w0.w + a.y * w1.w + a.z * w2.w + a.w * w3.w;
                        }
                    }
                }
#pragma unroll
                for (int r = 0; r < 8; ++r) {
                    int gi = i0 + g2 * 8 + r;
                    if (gi < p.N) {
                        float di = p.dis[gi];
                        float4 o;
                        o.x = di * LEAKY(acc[r].x); o.y = di * LEAKY(acc[r].y);
                        o.z = di * LEAKY(acc[r].z); o.w = di * LEAKY(acc[r].w);
                        __half2 h0 = __floats2half2_rn(o.x, o.y);
                        __half2 h1 = __floats2half2_rn(o.z, o.w);
                        uint2 u;
                        u.x = *(unsigned*)&h0;
                        u.y = *(unsigned*)&h1;
                        ((uint2*)p.ZA)[(size_t)gi * 24 + fq] = u;
                    }
                }
            }
            __syncthreads();
        }
    }
    grid.sync();

    // ---- 4 GCN layers: agg96 | gemm96 ----
    const float* Ws[4] = {p.W1, p.W2, p.W3, p.W4};
    const float* bs[4] = {p.b1, p.b2, p.b3, p.b4};
    __half* cur = p.ZA;
    __half* nxt = p.ZB;
    for (int l = 0; l < 4; ++l) {
        agg96(cur, p.dis, p.row_ptr, p.edge_src, p.Agg, p.N);
        grid.sync();
        if (l < 3)
            gemm96<1, 1>(p.Agg, Ws[l], bs[l], p.dis, nxt, p.N, Ah, Wt);
        else
            gemm96<0, 0>(p.Agg, Ws[l], bs[l], p.dis, p.H, p.N, Ah, Wt);
        grid.sync();
        __half* t = cur; cur = nxt; nxt = t;
    }

    // ---- Phase: pool_partial (G*8 chunks x 96 features) ----
    {
        int idx = blockIdx.x * 256 + threadIdx.x;
        int tot = p.G * 8 * 96;
        for (int ii = idx; ii < tot; ii += gridDim.x * 256) {
            int f = ii % 96;
            int pr = ii / 96;
            int g = pr / 8, ch = pr % 8;
            int s = lower_bound(p.batch, p.N, g), e = lower_bound(p.batch, p.N, g + 1);
            int len = e - s;
            int cs = s + (int)((long)len * ch / 8);
            int ce = s + (int)((long)len * (ch + 1) / 8);
            float mx = -INFINITY, sm = 0.f;
            for (int i = cs; i < ce; ++i) {
                float v = p.H[(size_t)i * 96 + f];
                mx = fmaxf(mx, v);
                sm += v;
            }
            p.pmax[(size_t)pr * 96 + f] = mx;
            p.psum[(size_t)pr * 96 + f] = sm;
        }
    }
    grid.sync();

    // ---- Phase: pool_final + MLP head (block g < G) ----
    if ((int)blockIdx.x < p.G) {
        float* pooled = (float*)smem;        // 192 floats
        float* sh = (float*)smem + 192;      // 96 floats
        int g = blockIdx.x, f = threadIdx.x;
        if (f < 96) {
            float mx = -INFINITY, sm = 0.f;
            for (int c = 0; c < 8; ++c) {
                mx = fmaxf(mx, p.pmax[(size_t)(g * 8 + c) * 96 + f]);
                sm += p.psum[(size_t)(g * 8 + c) * 96 + f];
            }
            int s = lower_bound(p.batch, p.N, g), e = lower_bound(p.batch, p.N, g + 1);
            float cnt = fmaxf((float)(e - s), 1.f);
            pooled[f] = mx;
            pooled[96 + f] = sm / cnt;
        }
        __syncthreads();
        if (f < 96) {
            float acc = p.bo1[f];
            for (int k = 0; k < 192; ++k) acc += pooled[k] * p.Wo1[k * 96 + f];
            float a = LEAKY(acc);
            sh[f] = a * p.Wo2[f];
        }
        __syncthreads();
        if (f == 0) {
            float sacc = 0.f;
            for (int k = 0; k < 96; ++k) sacc += sh[k];
            p.out[g] = sacc + p.bo2[0];
        }
    }
}

extern "C" void kernel_launch(void* const* d_in, const int* in_sizes, int n_in,
                              void* d_out, int out_size, void* d_ws, size_t ws_size,
                              hipStream_t stream) {
    const float* x      = (const float*)d_in[0];
    const int*   eidx   = (const int*)d_in[1];
    const int*   batch  = (const int*)d_in[2];
    const float* W_init = (const float*)d_in[3];
    const float* b_init = (const float*)d_in[4];
    const float* W1 = (const float*)d_in[5];  const float* b1 = (const float*)d_in[6];
    const float* W2 = (const float*)d_in[7];  const float* b2 = (const float*)d_in[8];
    const float* W3 = (const float*)d_in[9];  const float* b3 = (const float*)d_in[10];
    const float* W4 = (const float*)d_in[11]; const float* b4 = (const float*)d_in[12];
    const float* Wo1 = (const float*)d_in[13]; const float* bo1 = (const float*)d_in[14];
    const float* Wo2 = (const float*)d_in[15]; const float* bo2 = (const float*)d_in[16];
    float* out = (float*)d_out;

    const int N = in_sizes[2];
    const int E = in_sizes[1] / 2;
    const int G = out_size;
    const int* src = eidx;
    const int* dst = eidx + E;

    char* ws = (char*)d_ws;
    size_t off = 0;
    auto alloc = [&](size_t bytes) {
        size_t o = off;
        off += (bytes + 255) & ~(size_t)255;
        return o;
    };
    float* dis       = (float*)(ws + alloc((size_t)N * 4));
    int*   row_ptr   = (int*)(ws + alloc((size_t)(N + 1) * 4));
    int*   bfill     = (int*)(ws + alloc(NBMAX * 4));
    int*   edge_src  = (int*)(ws + alloc((size_t)E * 4));
    float* Z0        = (float*)(ws + alloc((size_t)N * 16 * 4));
    __half* ZA       = (__half*)(ws + alloc((size_t)N * 96 * 2));
    __half* ZB       = (__half*)(ws + alloc((size_t)N * 96 * 2));
    float* H         = (float*)(ws + alloc((size_t)N * 96 * 4));
    float* Agg       = (float*)(ws + alloc((size_t)N * 96 * 4));
    float* pmax      = (float*)(ws + alloc((size_t)G * 8 * 96 * 4));
    float* psum      = (float*)(ws + alloc((size_t)G * 8 * 96 * 4));
    uint2* tmp       = (uint2*)Agg;  // 12.8 MB < 19.2 MB; bin/place2 end before agg0
    (void)ws_size; (void)n_in;

    const int nbBkt  = (N + (1 << BK_SHIFT) - 1) >> BK_SHIFT;

    (void)hipMemsetAsync(bfill, 0, NBMAX * 4, stream);
    bin_kernel<<<(E + 2047) / 2048, 256, 0, stream>>>(src, dst, bfill, tmp, E, nbBkt);
    place2<<<nbBkt, 512, 0, stream>>>(tmp, bfill, x, dis, row_ptr, edge_src, Z0,
                                      4, N, E, nbBkt);

    MegaP mp;
    mp.dis = dis; mp.row_ptr = row_ptr; mp.edge_src = edge_src; mp.batch = batch;
    mp.Z0 = Z0; mp.ZA = ZA; mp.ZB = ZB; mp.H = H; mp.Agg = Agg;
    mp.pmax = pmax; mp.psum = psum;
    mp.W0 = W_init; mp.b0 = b_init;
    mp.W1 = W1; mp.b1 = b1; mp.W2 = W2; mp.b2 = b2;
    mp.W3 = W3; mp.b3 = b3; mp.W4 = W4; mp.b4 = b4;
    mp.Wo1 = Wo1; mp.bo1 = bo1; mp.Wo2 = Wo2; mp.bo2 = bo2;
    mp.out = out; mp.N = N; mp.G = G;

    int nbPerCU = 0;
    if (hipOccupancyMaxActiveBlocksPerMultiprocessor(&nbPerCU, gnn_mega, 256, 0)
            != hipSuccess || nbPerCU < 1)
        nbPerCU = 2;  // conservative fallback
    if (nbPerCU > 4) nbPerCU = 4;
    int grid = nbPerCU * 256;

    void* kargs[] = { (void*)&mp };
    (void)hipLaunchCooperativeKernel((const void*)gnn_mega, dim3(grid), dim3(256),
                                     kargs, 0, stream);
}